// Round 12
// baseline (992.626 us; speedup 1.0000x reference)
//
#include <hip/hip_runtime.h>
#include <stdint.h>
#include <stddef.h>

#define N_NODES 100000
#define N_EDGES 400000
#define NG      64
#define DIN     20
#define DH      1024
#define DFC     128
#define M_PAD   100096   // 782 * 128
#define MTILES  782
#define NBLK    391      // 391*256 = 100096 = M_PAD
#define CHUNK_T 128      // 128-row tiles per chunk; gemm grid = (128/2)*4 = 256 blocks = 1/CU

typedef __attribute__((ext_vector_type(8))) short bf16x8_t;  // 8 bf16 = 4 VGPR
typedef __attribute__((ext_vector_type(4))) float f32x4_t;

__device__ __forceinline__ float bf2f(uint32_t u){
  union { uint32_t i; float f; } v; v.i = u << 16; return v.f;   // takes LOW 16 bits
}
__device__ __forceinline__ uint32_t pk_bf16(float lo, float hi){
  uint32_t r;
  asm("v_cvt_pk_bf16_f32 %0, %1, %2" : "=v"(r) : "v"(lo), "v"(hi));
  return r;
}
__device__ __forceinline__ float tanhf_fast(float x){
  float t = __expf(2.0f * x);
  return 1.0f - 2.0f * __builtin_amdgcn_rcpf(1.0f + t);
}
__device__ __forceinline__ void gll16(const void* g, void* l){
  __builtin_amdgcn_global_load_lds(
      (const __attribute__((address_space(1))) unsigned int*)g,
      (__attribute__((address_space(3))) unsigned int*)l, 16, 0, 0);
}
__device__ __forceinline__ int xcd_swz(int bid, int nwg){
  if (nwg & 7) return bid;
  return (bid & 7) * (nwg >> 3) + (bid >> 3);
}

// ---------------- diagnostic fallback ----------------
__global__ void k_diag(float* __restrict__ out, float v){
  out[threadIdx.x] = v;
}

// ---------------- CSR build ----------------
__global__ void k_deg(const int* __restrict__ dstn, int* __restrict__ deg){
  int e = blockIdx.x * 256 + threadIdx.x;
  if (e < N_EDGES) atomicAdd(&deg[dstn[e]], 1);
}

__global__ void k_scan1(const int* __restrict__ deg, int* __restrict__ rowoff,
                        int* __restrict__ part){
  __shared__ int sb[256];
  const int t = threadIdx.x;
  const int n = blockIdx.x * 256 + t;
  int v = (n < N_NODES) ? deg[n] : 0;
  sb[t] = v;
  __syncthreads();
  for (int off = 1; off < 256; off <<= 1){
    int u = (t >= off) ? sb[t - off] : 0;
    __syncthreads();
    sb[t] += u;
    __syncthreads();
  }
  int incl = sb[t];
  if (n < N_NODES) rowoff[n] = incl - v;
  if (t == 255) part[blockIdx.x] = incl;
}

__global__ void k_scan2(int* part, int nblk){
  __shared__ int sb[512];
  const int t = threadIdx.x;
  int v = (t < nblk) ? part[t] : 0;
  sb[t] = v;
  __syncthreads();
  for (int off = 1; off < 512; off <<= 1){
    int u = (t >= off) ? sb[t - off] : 0;
    __syncthreads();
    sb[t] += u;
    __syncthreads();
  }
  if (t < nblk) part[t] = sb[t] - v;
}

__global__ void k_scan3(int* __restrict__ rowoff, const int* __restrict__ part){
  int n = blockIdx.x * 256 + threadIdx.x;
  if (n < N_NODES) rowoff[n] += part[blockIdx.x];
  if (n == 0) rowoff[N_NODES] = N_EDGES;
}

__global__ void k_fill(const int* __restrict__ src, const int* __restrict__ dstn,
                       const int* __restrict__ rowoff, int* __restrict__ cursor,
                       int* __restrict__ colx){
  int e = blockIdx.x * 256 + threadIdx.x;
  if (e < N_EDGES){
    int d = dstn[e];
    int p = rowoff[d] + atomicAdd(&cursor[d], 1);
    colx[p] = src[e];
  }
}

// ---------------- layer 1: pack A' = [mean_agg(x) | x | 0] as bf16 [M_PAD][64] ----------------
__global__ void k_pack(const float* __restrict__ x, const int* __restrict__ rowoff,
                       const int* __restrict__ colx, uint16_t* __restrict__ Ap){
  const int n = blockIdx.x * 256 + threadIdx.x;
  if (n >= M_PAD) return;
  uint4 o[8];
  if (n < N_NODES){
    f32x4_t a0 = {}, a1 = {}, a2 = {}, a3 = {}, a4 = {};
    const int e0 = rowoff[n], e1 = rowoff[n + 1];
    for (int e = e0; e < e1; e++){
      const f32x4_t* xr = (const f32x4_t*)(x + (size_t)colx[e] * DIN);
      a0 += xr[0]; a1 += xr[1]; a2 += xr[2]; a3 += xr[3]; a4 += xr[4];
    }
    const float inv = (e1 > e0) ? 1.f / (float)(e1 - e0) : 0.f;
    a0 *= inv; a1 *= inv; a2 *= inv; a3 *= inv; a4 *= inv;
    const f32x4_t* xs = (const f32x4_t*)(x + (size_t)n * DIN);
    f32x4_t b0 = xs[0], b1 = xs[1], b2 = xs[2], b3 = xs[3], b4 = xs[4];
    o[0] = make_uint4(pk_bf16(a0[0],a0[1]), pk_bf16(a0[2],a0[3]), pk_bf16(a1[0],a1[1]), pk_bf16(a1[2],a1[3]));
    o[1] = make_uint4(pk_bf16(a2[0],a2[1]), pk_bf16(a2[2],a2[3]), pk_bf16(a3[0],a3[1]), pk_bf16(a3[2],a3[3]));
    o[2] = make_uint4(pk_bf16(a4[0],a4[1]), pk_bf16(a4[2],a4[3]), pk_bf16(b0[0],b0[1]), pk_bf16(b0[2],b0[3]));
    o[3] = make_uint4(pk_bf16(b1[0],b1[1]), pk_bf16(b1[2],b1[3]), pk_bf16(b2[0],b2[1]), pk_bf16(b2[2],b2[3]));
    o[4] = make_uint4(pk_bf16(b3[0],b3[1]), pk_bf16(b3[2],b3[3]), pk_bf16(b4[0],b4[1]), pk_bf16(b4[2],b4[3]));
    o[5] = make_uint4(0,0,0,0); o[6] = o[5]; o[7] = o[5];
  } else {
    o[0] = make_uint4(0,0,0,0);
    for (int i = 1; i < 8; i++) o[i] = o[0];
  }
  uint4* dst = (uint4*)(Ap + (size_t)n * 64);
#pragma unroll
  for (int i = 0; i < 8; i++) dst[i] = o[i];
}

// fused weight prep: blocks 0..3 -> Bp = [W1l|W1r|0] bf16 [1024][64];
// blocks 4..2051 -> B2 combined [1024 out][2048 k] bf16: cols 0..1023 = W2l, 1024..2047 = W2r.
__global__ void k_prep(const float* __restrict__ W1l, const float* __restrict__ W1r,
                       uint16_t* __restrict__ Bp,
                       const float* __restrict__ W2l, const float* __restrict__ W2r,
                       uint16_t* __restrict__ B2){
  const int b = blockIdx.x;
  if (b < 4){
    const int j = b * 256 + threadIdx.x;
    if (j >= DH) return;
    const f32x4_t* wl = (const f32x4_t*)(W1l + (size_t)j * DIN);
    const f32x4_t* wr = (const f32x4_t*)(W1r + (size_t)j * DIN);
    f32x4_t a0 = wl[0], a1 = wl[1], a2 = wl[2], a3 = wl[3], a4 = wl[4];
    f32x4_t b0 = wr[0], b1 = wr[1], b2 = wr[2], b3 = wr[3], b4 = wr[4];
    uint4 o[8];
    o[0] = make_uint4(pk_bf16(a0[0],a0[1]), pk_bf16(a0[2],a0[3]), pk_bf16(a1[0],a1[1]), pk_bf16(a1[2],a1[3]));
    o[1] = make_uint4(pk_bf16(a2[0],a2[1]), pk_bf16(a2[2],a2[3]), pk_bf16(a3[0],a3[1]), pk_bf16(a3[2],a3[3]));
    o[2] = make_uint4(pk_bf16(a4[0],a4[1]), pk_bf16(a4[2],a4[3]), pk_bf16(b0[0],b0[1]), pk_bf16(b0[2],b0[3]));
    o[3] = make_uint4(pk_bf16(b1[0],b1[1]), pk_bf16(b1[2],b1[3]), pk_bf16(b2[0],b2[1]), pk_bf16(b2[2],b2[3]));
    o[4] = make_uint4(pk_bf16(b3[0],b3[1]), pk_bf16(b3[2],b3[3]), pk_bf16(b4[0],b4[1]), pk_bf16(b4[2],b4[3]));
    o[5] = make_uint4(0,0,0,0); o[6] = o[5]; o[7] = o[5];
    uint4* dst = (uint4*)(Bp + (size_t)j * 64);
#pragma unroll
    for (int i = 0; i < 8; i++) dst[i] = o[i];
    return;
  }
  int q = (b - 4) * 256 + threadIdx.x;      // quad index over both matrices
  const int sel = q >= 262144;              // 0 = W2l, 1 = W2r
  if (sel) q -= 262144;
  const int j = q >> 8;                     // out row
  const int k4 = (q & 255) * 4;             // k col (4 elems)
  const float* w = sel ? W2r : W2l;
  float4 f = *(const float4*)(w + (size_t)j * 1024 + k4);
  uint2 o;
  o.x = pk_bf16(f.x, f.y);
  o.y = pk_bf16(f.z, f.w);
  *(uint2*)(B2 + (size_t)j * 2048 + sel * 1024 + k4) = o;
}

// layer-1 GEMM: h1 = tanh(A' @ B'^T + b1l), M=M_PAD, N=1024, K=64.
__global__ __launch_bounds__(256) void k_l1g(
    const uint16_t* __restrict__ Ap, const uint16_t* __restrict__ Bp,
    const float* __restrict__ bias, uint16_t* __restrict__ h1)
{
  __shared__ uint16_t lds[16384];
  const int wg = xcd_swz(blockIdx.x, gridDim.x);
  const int mt = wg >> 3, jt = wg & 7;
  const int tid = threadIdx.x;
  const int lane = tid & 63, w = tid >> 6;
  const int wm = w >> 1, wn = w & 1;
  char* ldsb = (char*)lds;

  const int rgrp = lane >> 3;
  const int sl   = lane & 7;
  const int sw   = sl ^ rgrp;
#pragma unroll
  for (int t = 0; t < 4; t++){
    const int r0 = w * 32 + t * 8;
    gll16((const char*)Ap + (size_t)(mt * 128 + r0 + rgrp) * 128 + sw * 16,
          ldsb + r0 * 128);
    gll16((const char*)Bp + (size_t)(jt * 128 + r0 + rgrp) * 128 + sw * 16,
          ldsb + 16384 + r0 * 128);
  }
  __syncthreads();

  f32x4_t acc[4][4] = {};
  const int ks = lane >> 4;
  const int rA = wm * 64 + (lane & 15);
  const int rB = wn * 64 + (lane & 15);
#pragma unroll
  for (int kt = 0; kt < 2; kt++){
    bf16x8_t af[4], bg[4];
#pragma unroll
    for (int mi = 0; mi < 4; mi++){
      int r = rA + mi * 16;
      af[mi] = *(const bf16x8_t*)(ldsb + r * 128 + (((kt * 4 + ks) ^ (r & 7)) << 4));
    }
#pragma unroll
    for (int ni = 0; ni < 4; ni++){
      int r = rB + ni * 16;
      bg[ni] = *(const bf16x8_t*)(ldsb + 16384 + r * 128 + (((kt * 4 + ks) ^ (r & 7)) << 4));
    }
#pragma unroll
    for (int mi = 0; mi < 4; mi++)
#pragma unroll
      for (int ni = 0; ni < 4; ni++)
        acc[mi][ni] = __builtin_amdgcn_mfma_f32_16x16x32_bf16(bg[ni], af[mi], acc[mi][ni], 0, 0, 0);
  }

  __syncthreads();
  const int c4 = (lane >> 4) * 4;
#pragma unroll
  for (int ni = 0; ni < 4; ni++){
    const int colL = wn * 64 + ni * 16 + c4;
    const f32x4_t bs = *(const f32x4_t*)(bias + jt * 128 + colL);
    const int b16 = colL >> 3;
    const int hh  = (colL >> 2) & 1;
#pragma unroll
    for (int mi = 0; mi < 4; mi++){
      const int r = wm * 64 + mi * 16 + (lane & 15);
      uint2 o;
      o.x = pk_bf16(tanhf_fast(acc[mi][ni][0] + bs[0]), tanhf_fast(acc[mi][ni][1] + bs[1]));
      o.y = pk_bf16(tanhf_fast(acc[mi][ni][2] + bs[2]), tanhf_fast(acc[mi][ni][3] + bs[3]));
      *(uint2*)(ldsb + r * 256 + ((b16 ^ (r & 15)) << 4) + hh * 8) = o;
    }
  }
  __syncthreads();
  char* dst0 = (char*)(h1 + (size_t)(mt * 128) * DH + jt * 128);
#pragma unroll
  for (int k = 0; k < 8; k++){
    const int c = tid + k * 256;
    const int r = c >> 4, b16 = c & 15;
    uint4 v = *(const uint4*)(ldsb + r * 256 + ((b16 ^ (r & 15)) << 4));
    *(uint4*)(dst0 + (size_t)r * DH * 2 + b16 * 16) = v;
  }
}

// ---------------- layer 2 aggregation (CSR gather of bf16 h1), chunked ----------------
__global__ void k_agg2(const uint16_t* __restrict__ h1, const int* __restrict__ rowoff,
                       const int* __restrict__ colx, uint16_t* __restrict__ aggc,
                       int row0){
  const int half = threadIdx.x >> 7;
  const int t = threadIdx.x & 127;
  const int nl = blockIdx.x * 2 + half;
  const int n = row0 + nl;
  uint4* out = (uint4*)aggc;
  const size_t ro = (size_t)nl * 128 + t;
  if (n >= N_NODES){ out[ro] = make_uint4(0u,0u,0u,0u); return; }
  const int e0 = rowoff[n], e1 = rowoff[n + 1];
  float f0=0.f,f1=0.f,f2=0.f,f3=0.f,f4=0.f,f5=0.f,f6=0.f,f7=0.f;
  const uint4* H = (const uint4*)h1;
  for (int e = e0; e < e1; e++){
    uint4 u = H[(size_t)colx[e] * 128 + t];
    f0 += bf2f(u.x); f1 += bf2f(u.x >> 16);
    f2 += bf2f(u.y); f3 += bf2f(u.y >> 16);
    f4 += bf2f(u.z); f5 += bf2f(u.z >> 16);
    f6 += bf2f(u.w); f7 += bf2f(u.w >> 16);
  }
  const float inv = (e1 > e0) ? 1.f / (float)(e1 - e0) : 0.f;
  uint4 o;
  o.x = pk_bf16(f0 * inv, f1 * inv);
  o.y = pk_bf16(f2 * inv, f3 * inv);
  o.z = pk_bf16(f4 * inv, f5 * inv);
  o.w = pk_bf16(f6 * inv, f7 * inv);
  out[ro] = o;
}

// ---------------- layer 2 GEMM: 256x256 tile, BK=64, 8 waves, B direct from L2 ----------------
// C = tanh([aggc|h1c] @ [W2l|W2r]^T + b2l), fused pooling. K = 2048 = 32 K-tiles of 64.
// A staged in LDS (2 x 32KB double-buffer, gll16); B fragments loaded DIRECTLY global->reg
// (B2 = 4MB, L2-resident; per-lane fragment is a contiguous 16B dwordx4 in row-major B2:
// the old LDS path stored LDS[r][s]=g[r][s^(r&7)] and read slot ks^(r&7) = plain slot ks).
// Single __syncthreads per K-tile: vmcnt(0) drain covers exactly {A-stage(kt+1), bgN(kt+1)}
// — all needed next tile, issued ~1 tile earlier -> landed; drain is semantically exact.
// Dbuf hazard: stage(kt+1) at top of kt targets buf[(kt+1)&1], whose kt-1 readers finished
// at the last barrier. LDS reads cut 24->16 per wave per K-tile (the measured serial cost).
__global__ __launch_bounds__(512) void k_gemm(
    const uint16_t* __restrict__ A0, const uint16_t* __restrict__ A1,
    const uint16_t* __restrict__ B2, const float* __restrict__ bias,
    const int* __restrict__ batch, float* __restrict__ gbuf, int row0)
{
  __shared__ char ldsb[65536];              // 2 x 32KB A buffers
  const int wg = xcd_swz(blockIdx.x, gridDim.x);
  const int mt = wg >> 2, jtg = wg & 3;     // mt: chunk-local 256-row tile; jtg: 256 cols
  const int tid = threadIdx.x;
  const int lane = tid & 63, w = tid >> 6;  // 8 waves
  const int wm = w >> 2, wn = w & 3;        // 2 x 4 wave grid; wave output 128 x 64

  const int aw_row = w * 8 + (lane >> 3);
  const size_t slotb = (size_t)(((lane & 7) ^ (lane >> 3)) << 4);

  // stage full A K-tile (256x64 bf16 = 32KB) into buf t2&1; LDS layout linear r*128+s*16
  // with LDS[r][s] = global[r][s ^ (r&7)] (per-8-row slot swizzle via pre-swizzled source)
  auto stageA = [&](int t2){
    const char* gb = (t2 < 16) ? (const char*)A0 : (const char*)A1;
    const size_t ktc = (size_t)(t2 & 15) * 128;
    char* lb = ldsb + (t2 & 1) * 32768 + w * 1024;
    const size_t r0 = (size_t)(mt * 256 + aw_row);
    gll16(gb + r0 * 2048 + ktc + slotb, lb);
    gll16(gb + (r0 + 64) * 2048 + ktc + slotb, lb + 8192);
    gll16(gb + (r0 + 128) * 2048 + ktc + slotb, lb + 16384);
    gll16(gb + (r0 + 192) * 2048 + ktc + slotb, lb + 24576);
  };

  const int ks = lane >> 4;
  // B fragment base: row = jtg*256 + wn*64 + n*16 + (lane&15), frag q at kt*128 + (q*4+ks)*16
  const char* Bg = (const char*)B2
                 + (size_t)(jtg * 256 + wn * 64 + (lane & 15)) * 4096 + ((size_t)ks << 4);

  bf16x8_t bg[8], bgN[8];
  // prologue: A tiles 0,1 staged; B tile 0 loaded
  stageA(0);
#pragma unroll
  for (int n = 0; n < 4; n++)
#pragma unroll
    for (int q = 0; q < 2; q++)
      bg[n * 2 + q] = *(const bf16x8_t*)(Bg + (size_t)n * 65536 + q * 64);
  stageA(1);
  __syncthreads();

  f32x4_t acc[8][4] = {};
  const int rA = wm * 128 + (lane & 15);

  for (int kt = 0; kt < 32; ++kt){
    const char* lA = ldsb + (kt & 1) * 32768;
    // prefetch next B tile (L2 hit, compiler-managed waits)
    if (kt < 31){
#pragma unroll
      for (int n = 0; n < 4; n++)
#pragma unroll
        for (int q = 0; q < 2; q++)
          bgN[n * 2 + q] = *(const bf16x8_t*)(Bg + (size_t)n * 65536
                                              + (size_t)(kt + 1) * 128 + q * 64);
    }
    // stage next A tile into the buffer freed at the last barrier
    if (kt < 31) stageA(kt + 1);
    // A operands for this tile (16 ds_read_b128; compiler overlaps with MFMA below)
    bf16x8_t af[8][2];
#pragma unroll
    for (int m = 0; m < 8; m++){
      int r = rA + m * 16;
      af[m][0] = *(const bf16x8_t*)(lA + r * 128 + ((ks ^ (r & 7)) << 4));
      af[m][1] = *(const bf16x8_t*)(lA + r * 128 + (((4 + ks) ^ (r & 7)) << 4));
    }
#pragma unroll
    for (int m = 0; m < 8; m++)
#pragma unroll
      for (int n = 0; n < 4; n++){
        acc[m][n] = __builtin_amdgcn_mfma_f32_16x16x32_bf16(af[m][0], bg[n * 2 + 0], acc[m][n], 0, 0, 0);
        acc[m][n] = __builtin_amdgcn_mfma_f32_16x16x32_bf16(af[m][1], bg[n * 2 + 1], acc[m][n], 0, 0, 0);
      }
    __syncthreads();   // vmcnt(0)+lgkmcnt(0) drain: stage(kt+1)+bgN landed; buf[cur] free
    if (kt < 31){
#pragma unroll
      for (int i = 0; i < 8; i++) bg[i] = bgN[i];
    }
  }

  // epilogue: bias + tanh + segmented pooling (batch sorted)
  const int rowbase = row0 + mt * 256 + wm * 128;
  const int colbase = jtg * 256 + wn * 64;
  int bt[8][4];
#pragma unroll
  for (int mi = 0; mi < 8; mi++)
#pragma unroll
    for (int i = 0; i < 4; i++){
      int R = rowbase + mi * 16 + (lane >> 4) * 4 + i;
      bt[mi][i] = (R < N_NODES) ? batch[R] : -1;
    }
  const int c0 = rowbase       < N_NODES ? rowbase       : N_NODES - 1;
  const int c1 = rowbase + 127 < N_NODES ? rowbase + 127 : N_NODES - 1;
  const int gmin = batch[c0], gmax = batch[c1];

#pragma unroll
  for (int ni = 0; ni < 4; ni++){
    const int col = colbase + ni * 16 + (lane & 15);
    const float bs = bias[col];
    float v[8][4];
#pragma unroll
    for (int mi = 0; mi < 8; mi++)
#pragma unroll
      for (int i = 0; i < 4; i++)
        v[mi][i] = tanhf_fast(acc[mi][ni][i] + bs);
    for (int g = gmin; g <= gmax; g++){
      float s_ = 0.f;
#pragma unroll
      for (int mi = 0; mi < 8; mi++)
#pragma unroll
        for (int i = 0; i < 4; i++)
          s_ += (bt[mi][i] == g) ? v[mi][i] : 0.f;
      s_ += __shfl_xor(s_, 16);
      s_ += __shfl_xor(s_, 32);
      if (lane < 16) atomicAdd(&gbuf[g * DH + col], s_);
    }
  }
}

// ---------------- MLP head ----------------
__global__ void k_head(const float* __restrict__ gbuf, const float* __restrict__ Wf1,
                       const float* __restrict__ bf1, const float* __restrict__ Wf2,
                       const float* __restrict__ bf2, float* __restrict__ out){
  const int gg = blockIdx.x, j = threadIdx.x;
  const float* grow = gbuf + (size_t)gg * DH;
  const float* wr = Wf1 + (size_t)j * DH;
  float acc = bf1[j];
  for (int k = 0; k < DH; k++) acc = fmaf(grow[k], wr[k], acc);
  float y = acc > 0.f ? acc : 0.2f * acc;
  __shared__ float sb[DFC];
  sb[j] = y * Wf2[j];
  __syncthreads();
  for (int off = 64; off > 0; off >>= 1){
    if (j < off) sb[j] += sb[j + off];
    __syncthreads();
  }
  if (j == 0) out[gg] = sb[0] + bf2[0];
}

extern "C" void kernel_launch(void* const* d_in, const int* in_sizes, int n_in,
                              void* d_out, int out_size, void* d_ws, size_t ws_size,
                              hipStream_t stream){
  const float* x   = (const float*)d_in[0];
  const int*   ei  = (const int*)d_in[1];
  const int*   src = ei;
  const int*   dst = ei + N_EDGES;
  const int*   batch = (const int*)d_in[2];
  const float* W1l = (const float*)d_in[3];
  const float* b1l = (const float*)d_in[4];
  const float* W1r = (const float*)d_in[5];
  const float* W2l = (const float*)d_in[6];
  const float* b2l = (const float*)d_in[7];
  const float* W2r = (const float*)d_in[8];
  const float* Wf1 = (const float*)d_in[9];
  const float* bf1 = (const float*)d_in[10];
  const float* Wf2 = (const float*)d_in[11];
  const float* bf2 = (const float*)d_in[12];
  float* out = (float*)d_out;
  (void)in_sizes; (void)n_in; (void)out_size;

  char* ws = (char*)d_ws;
  size_t off = 0;
  auto alloc = [&](size_t bytes) -> void* {
    void* p = (void*)(ws + off);
    off = (off + bytes + 255) & ~(size_t)255;
    return p;
  };
  uint16_t* h1   = (uint16_t*)alloc((size_t)M_PAD * DH * 2);   // 205 MB
  uint16_t* Ap   = (uint16_t*)alloc((size_t)M_PAD * 64 * 2);   // 12.8 MB
  uint16_t* Bp   = (uint16_t*)alloc((size_t)DH * 64 * 2);      // 128 KB
  uint16_t* B2   = (uint16_t*)alloc((size_t)DH * 2048 * 2);    // 4 MB combined [W2l|W2r]
  int*      deg  = (int*)alloc((size_t)N_NODES * 4);
  int*      curs = (int*)alloc((size_t)N_NODES * 4);
  float*    gbuf = (float*)alloc((size_t)NG * DH * 4);
  int*      rowo = (int*)alloc((size_t)(N_NODES + 1) * 4);
  int*      colx = (int*)alloc((size_t)N_EDGES * 4);
  int*      part = (int*)alloc((size_t)NBLK * 4);
  long long remain = (long long)ws_size - (long long)off;
  int chunk_t = (int)(remain / (128LL * 2048LL));
  if (chunk_t > CHUNK_T) chunk_t = CHUNK_T;
  chunk_t &= ~1;                             // gemm tiles are 256 rows = 2 chunk units
  if (chunk_t < 2){
    k_diag<<<1, 64, 0, stream>>>(out, (float)ws_size);
    return;
  }
  uint16_t* aggc = (uint16_t*)alloc((size_t)chunk_t * 128 * DH * 2);

  const size_t zset = (size_t)((char*)gbuf - (char*)deg) + (size_t)NG * DH * 4;
  hipMemsetAsync(deg, 0, zset, stream);   // deg + curs + gbuf in one shot

  k_deg  <<<(N_EDGES + 255) / 256, 256, 0, stream>>>(dst, deg);
  k_scan1<<<NBLK, 256, 0, stream>>>(deg, rowo, part);
  k_scan2<<<1, 512, 0, stream>>>(part, NBLK);
  k_scan3<<<NBLK, 256, 0, stream>>>(rowo, part);
  k_fill <<<(N_EDGES + 255) / 256, 256, 0, stream>>>(src, dst, rowo, curs, colx);
  k_pack <<<NBLK, 256, 0, stream>>>(x, rowo, colx, Ap);
  k_prep <<<4 + 2048, 256, 0, stream>>>(W1l, W1r, Bp, W2l, W2r, B2);
  k_l1g  <<<MTILES * 8, 256, 0, stream>>>(Ap, Bp, b1l, h1);

  for (int t0 = 0; t0 < MTILES; ){
    int ct = MTILES - t0 < chunk_t ? MTILES - t0 : chunk_t;
    int row0 = t0 * 128;
    k_agg2<<<ct * 64, 256, 0, stream>>>(h1, rowo, colx, aggc, row0);
    k_gemm<<<(ct / 2) * 4, 512, 0, stream>>>(aggc, h1 + (size_t)row0 * DH,
                                             B2, b2l, batch, gbuf, row0);
    t0 += ct;
  }
  k_head <<<NG, DFC, 0, stream>>>(gbuf, Wf1, bf1, Wf2, bf2, out);
}

// Round 13
// 750.082 us; speedup vs baseline: 1.3234x; 1.3234x over previous
//
#include <hip/hip_runtime.h>
#include <stdint.h>
#include <stddef.h>

#define N_NODES 100000
#define N_EDGES 400000
#define NG      64
#define DIN     20
#define DH      1024
#define DFC     128
#define M_PAD   100096   // 782 * 128
#define MTILES  782
#define NBLK    391      // 391*256 = 100096 = M_PAD
#define CHUNK_T 128      // 128-row tiles per chunk; gemm grid = (128/2)*4 = 256 blocks = 1/CU

typedef __attribute__((ext_vector_type(8))) short bf16x8_t;  // 8 bf16 = 4 VGPR
typedef __attribute__((ext_vector_type(4))) float f32x4_t;

__device__ __forceinline__ float bf2f(uint32_t u){
  union { uint32_t i; float f; } v; v.i = u << 16; return v.f;   // takes LOW 16 bits
}
__device__ __forceinline__ uint32_t pk_bf16(float lo, float hi){
  uint32_t r;
  asm("v_cvt_pk_bf16_f32 %0, %1, %2" : "=v"(r) : "v"(lo), "v"(hi));
  return r;
}
__device__ __forceinline__ float tanhf_fast(float x){
  float t = __expf(2.0f * x);
  return 1.0f - 2.0f * __builtin_amdgcn_rcpf(1.0f + t);
}
__device__ __forceinline__ void gll16(const void* g, void* l){
  __builtin_amdgcn_global_load_lds(
      (const __attribute__((address_space(1))) unsigned int*)g,
      (__attribute__((address_space(3))) unsigned int*)l, 16, 0, 0);
}
__device__ __forceinline__ int xcd_swz(int bid, int nwg){
  if (nwg & 7) return bid;
  return (bid & 7) * (nwg >> 3) + (bid >> 3);
}
#define BARRIER() asm volatile("s_barrier" ::: "memory")

// ---------------- diagnostic fallback ----------------
__global__ void k_diag(float* __restrict__ out, float v){
  out[threadIdx.x] = v;
}

// ---------------- CSR build ----------------
__global__ void k_deg(const int* __restrict__ dstn, int* __restrict__ deg){
  int e = blockIdx.x * 256 + threadIdx.x;
  if (e < N_EDGES) atomicAdd(&deg[dstn[e]], 1);
}

__global__ void k_scan1(const int* __restrict__ deg, int* __restrict__ rowoff,
                        int* __restrict__ part){
  __shared__ int sb[256];
  const int t = threadIdx.x;
  const int n = blockIdx.x * 256 + t;
  int v = (n < N_NODES) ? deg[n] : 0;
  sb[t] = v;
  __syncthreads();
  for (int off = 1; off < 256; off <<= 1){
    int u = (t >= off) ? sb[t - off] : 0;
    __syncthreads();
    sb[t] += u;
    __syncthreads();
  }
  int incl = sb[t];
  if (n < N_NODES) rowoff[n] = incl - v;
  if (t == 255) part[blockIdx.x] = incl;
}

__global__ void k_scan2(int* part, int nblk){
  __shared__ int sb[512];
  const int t = threadIdx.x;
  int v = (t < nblk) ? part[t] : 0;
  sb[t] = v;
  __syncthreads();
  for (int off = 1; off < 512; off <<= 1){
    int u = (t >= off) ? sb[t - off] : 0;
    __syncthreads();
    sb[t] += u;
    __syncthreads();
  }
  if (t < nblk) part[t] = sb[t] - v;
}

__global__ void k_scan3(int* __restrict__ rowoff, const int* __restrict__ part){
  int n = blockIdx.x * 256 + threadIdx.x;
  if (n < N_NODES) rowoff[n] += part[blockIdx.x];
  if (n == 0) rowoff[N_NODES] = N_EDGES;
}

__global__ void k_fill(const int* __restrict__ src, const int* __restrict__ dstn,
                       const int* __restrict__ rowoff, int* __restrict__ cursor,
                       int* __restrict__ colx){
  int e = blockIdx.x * 256 + threadIdx.x;
  if (e < N_EDGES){
    int d = dstn[e];
    int p = rowoff[d] + atomicAdd(&cursor[d], 1);
    colx[p] = src[e];
  }
}

// ---------------- layer 1: pack A' = [mean_agg(x) | x | 0] as bf16 [M_PAD][64] ----------------
__global__ void k_pack(const float* __restrict__ x, const int* __restrict__ rowoff,
                       const int* __restrict__ colx, uint16_t* __restrict__ Ap){
  const int n = blockIdx.x * 256 + threadIdx.x;
  if (n >= M_PAD) return;
  uint4 o[8];
  if (n < N_NODES){
    f32x4_t a0 = {}, a1 = {}, a2 = {}, a3 = {}, a4 = {};
    const int e0 = rowoff[n], e1 = rowoff[n + 1];
    for (int e = e0; e < e1; e++){
      const f32x4_t* xr = (const f32x4_t*)(x + (size_t)colx[e] * DIN);
      a0 += xr[0]; a1 += xr[1]; a2 += xr[2]; a3 += xr[3]; a4 += xr[4];
    }
    const float inv = (e1 > e0) ? 1.f / (float)(e1 - e0) : 0.f;
    a0 *= inv; a1 *= inv; a2 *= inv; a3 *= inv; a4 *= inv;
    const f32x4_t* xs = (const f32x4_t*)(x + (size_t)n * DIN);
    f32x4_t b0 = xs[0], b1 = xs[1], b2 = xs[2], b3 = xs[3], b4 = xs[4];
    o[0] = make_uint4(pk_bf16(a0[0],a0[1]), pk_bf16(a0[2],a0[3]), pk_bf16(a1[0],a1[1]), pk_bf16(a1[2],a1[3]));
    o[1] = make_uint4(pk_bf16(a2[0],a2[1]), pk_bf16(a2[2],a2[3]), pk_bf16(a3[0],a3[1]), pk_bf16(a3[2],a3[3]));
    o[2] = make_uint4(pk_bf16(a4[0],a4[1]), pk_bf16(a4[2],a4[3]), pk_bf16(b0[0],b0[1]), pk_bf16(b0[2],b0[3]));
    o[3] = make_uint4(pk_bf16(b1[0],b1[1]), pk_bf16(b1[2],b1[3]), pk_bf16(b2[0],b2[1]), pk_bf16(b2[2],b2[3]));
    o[4] = make_uint4(pk_bf16(b3[0],b3[1]), pk_bf16(b3[2],b3[3]), pk_bf16(b4[0],b4[1]), pk_bf16(b4[2],b4[3]));
    o[5] = make_uint4(0,0,0,0); o[6] = o[5]; o[7] = o[5];
  } else {
    o[0] = make_uint4(0,0,0,0);
    for (int i = 1; i < 8; i++) o[i] = o[0];
  }
  uint4* dst = (uint4*)(Ap + (size_t)n * 64);
#pragma unroll
  for (int i = 0; i < 8; i++) dst[i] = o[i];
}

// fused weight prep: blocks 0..3 -> Bp = [W1l|W1r|0] bf16 [1024][64];
// blocks 4..2051 -> B2 combined [1024 out][2048 k] bf16: cols 0..1023 = W2l, 1024..2047 = W2r.
__global__ void k_prep(const float* __restrict__ W1l, const float* __restrict__ W1r,
                       uint16_t* __restrict__ Bp,
                       const float* __restrict__ W2l, const float* __restrict__ W2r,
                       uint16_t* __restrict__ B2){
  const int b = blockIdx.x;
  if (b < 4){
    const int j = b * 256 + threadIdx.x;
    if (j >= DH) return;
    const f32x4_t* wl = (const f32x4_t*)(W1l + (size_t)j * DIN);
    const f32x4_t* wr = (const f32x4_t*)(W1r + (size_t)j * DIN);
    f32x4_t a0 = wl[0], a1 = wl[1], a2 = wl[2], a3 = wl[3], a4 = wl[4];
    f32x4_t b0 = wr[0], b1 = wr[1], b2 = wr[2], b3 = wr[3], b4 = wr[4];
    uint4 o[8];
    o[0] = make_uint4(pk_bf16(a0[0],a0[1]), pk_bf16(a0[2],a0[3]), pk_bf16(a1[0],a1[1]), pk_bf16(a1[2],a1[3]));
    o[1] = make_uint4(pk_bf16(a2[0],a2[1]), pk_bf16(a2[2],a2[3]), pk_bf16(a3[0],a3[1]), pk_bf16(a3[2],a3[3]));
    o[2] = make_uint4(pk_bf16(a4[0],a4[1]), pk_bf16(a4[2],a4[3]), pk_bf16(b0[0],b0[1]), pk_bf16(b0[2],b0[3]));
    o[3] = make_uint4(pk_bf16(b1[0],b1[1]), pk_bf16(b1[2],b1[3]), pk_bf16(b2[0],b2[1]), pk_bf16(b2[2],b2[3]));
    o[4] = make_uint4(pk_bf16(b3[0],b3[1]), pk_bf16(b3[2],b3[3]), pk_bf16(b4[0],b4[1]), pk_bf16(b4[2],b4[3]));
    o[5] = make_uint4(0,0,0,0); o[6] = o[5]; o[7] = o[5];
    uint4* dst = (uint4*)(Bp + (size_t)j * 64);
#pragma unroll
    for (int i = 0; i < 8; i++) dst[i] = o[i];
    return;
  }
  int q = (b - 4) * 256 + threadIdx.x;      // quad index over both matrices
  const int sel = q >= 262144;              // 0 = W2l, 1 = W2r
  if (sel) q -= 262144;
  const int j = q >> 8;                     // out row
  const int k4 = (q & 255) * 4;             // k col (4 elems)
  const float* w = sel ? W2r : W2l;
  float4 f = *(const float4*)(w + (size_t)j * 1024 + k4);
  uint2 o;
  o.x = pk_bf16(f.x, f.y);
  o.y = pk_bf16(f.z, f.w);
  *(uint2*)(B2 + (size_t)j * 2048 + sel * 1024 + k4) = o;
}

// layer-1 GEMM: h1 = tanh(A' @ B'^T + b1l), M=M_PAD, N=1024, K=64.
__global__ __launch_bounds__(256) void k_l1g(
    const uint16_t* __restrict__ Ap, const uint16_t* __restrict__ Bp,
    const float* __restrict__ bias, uint16_t* __restrict__ h1)
{
  __shared__ uint16_t lds[16384];
  const int wg = xcd_swz(blockIdx.x, gridDim.x);
  const int mt = wg >> 3, jt = wg & 7;
  const int tid = threadIdx.x;
  const int lane = tid & 63, w = tid >> 6;
  const int wm = w >> 1, wn = w & 1;
  char* ldsb = (char*)lds;

  const int rgrp = lane >> 3;
  const int sl   = lane & 7;
  const int sw   = sl ^ rgrp;
#pragma unroll
  for (int t = 0; t < 4; t++){
    const int r0 = w * 32 + t * 8;
    gll16((const char*)Ap + (size_t)(mt * 128 + r0 + rgrp) * 128 + sw * 16,
          ldsb + r0 * 128);
    gll16((const char*)Bp + (size_t)(jt * 128 + r0 + rgrp) * 128 + sw * 16,
          ldsb + 16384 + r0 * 128);
  }
  __syncthreads();

  f32x4_t acc[4][4] = {};
  const int ks = lane >> 4;
  const int rA = wm * 64 + (lane & 15);
  const int rB = wn * 64 + (lane & 15);
#pragma unroll
  for (int kt = 0; kt < 2; kt++){
    bf16x8_t af[4], bg[4];
#pragma unroll
    for (int mi = 0; mi < 4; mi++){
      int r = rA + mi * 16;
      af[mi] = *(const bf16x8_t*)(ldsb + r * 128 + (((kt * 4 + ks) ^ (r & 7)) << 4));
    }
#pragma unroll
    for (int ni = 0; ni < 4; ni++){
      int r = rB + ni * 16;
      bg[ni] = *(const bf16x8_t*)(ldsb + 16384 + r * 128 + (((kt * 4 + ks) ^ (r & 7)) << 4));
    }
#pragma unroll
    for (int mi = 0; mi < 4; mi++)
#pragma unroll
      for (int ni = 0; ni < 4; ni++)
        acc[mi][ni] = __builtin_amdgcn_mfma_f32_16x16x32_bf16(bg[ni], af[mi], acc[mi][ni], 0, 0, 0);
  }

  __syncthreads();
  const int c4 = (lane >> 4) * 4;
#pragma unroll
  for (int ni = 0; ni < 4; ni++){
    const int colL = wn * 64 + ni * 16 + c4;
    const f32x4_t bs = *(const f32x4_t*)(bias + jt * 128 + colL);
    const int b16 = colL >> 3;
    const int hh  = (colL >> 2) & 1;
#pragma unroll
    for (int mi = 0; mi < 4; mi++){
      const int r = wm * 64 + mi * 16 + (lane & 15);
      uint2 o;
      o.x = pk_bf16(tanhf_fast(acc[mi][ni][0] + bs[0]), tanhf_fast(acc[mi][ni][1] + bs[1]));
      o.y = pk_bf16(tanhf_fast(acc[mi][ni][2] + bs[2]), tanhf_fast(acc[mi][ni][3] + bs[3]));
      *(uint2*)(ldsb + r * 256 + ((b16 ^ (r & 15)) << 4) + hh * 8) = o;
    }
  }
  __syncthreads();
  char* dst0 = (char*)(h1 + (size_t)(mt * 128) * DH + jt * 128);
#pragma unroll
  for (int k = 0; k < 8; k++){
    const int c = tid + k * 256;
    const int r = c >> 4, b16 = c & 15;
    uint4 v = *(const uint4*)(ldsb + r * 256 + ((b16 ^ (r & 15)) << 4));
    *(uint4*)(dst0 + (size_t)r * DH * 2 + b16 * 16) = v;
  }
}

// ---------------- layer 2 aggregation (CSR gather of bf16 h1), chunked ----------------
__global__ void k_agg2(const uint16_t* __restrict__ h1, const int* __restrict__ rowoff,
                       const int* __restrict__ colx, uint16_t* __restrict__ aggc,
                       int row0){
  const int half = threadIdx.x >> 7;
  const int t = threadIdx.x & 127;
  const int nl = blockIdx.x * 2 + half;
  const int n = row0 + nl;
  uint4* out = (uint4*)aggc;
  const size_t ro = (size_t)nl * 128 + t;
  if (n >= N_NODES){ out[ro] = make_uint4(0u,0u,0u,0u); return; }
  const int e0 = rowoff[n], e1 = rowoff[n + 1];
  float f0=0.f,f1=0.f,f2=0.f,f3=0.f,f4=0.f,f5=0.f,f6=0.f,f7=0.f;
  const uint4* H = (const uint4*)h1;
  for (int e = e0; e < e1; e++){
    uint4 u = H[(size_t)colx[e] * 128 + t];
    f0 += bf2f(u.x); f1 += bf2f(u.x >> 16);
    f2 += bf2f(u.y); f3 += bf2f(u.y >> 16);
    f4 += bf2f(u.z); f5 += bf2f(u.z >> 16);
    f6 += bf2f(u.w); f7 += bf2f(u.w >> 16);
  }
  const float inv = (e1 > e0) ? 1.f / (float)(e1 - e0) : 0.f;
  uint4 o;
  o.x = pk_bf16(f0 * inv, f1 * inv);
  o.y = pk_bf16(f2 * inv, f3 * inv);
  o.z = pk_bf16(f4 * inv, f5 * inv);
  o.w = pk_bf16(f6 * inv, f7 * inv);
  out[ro] = o;
}

// ---------------- layer 2 GEMM: phase-interleaved 256x256 tile, BK=64, 8 waves ----------------
// (R10-verified best: 69.6 us/chunk, MfmaUtil 40%.) 4 phases per K-tile; counted vmcnt(6);
// see R10 hazard audit in history. C = tanh([aggc|h1c] @ [W2l|W2r]^T + b2l), fused pooling.
__global__ __launch_bounds__(512) void k_gemm(
    const uint16_t* __restrict__ A0, const uint16_t* __restrict__ A1,
    const uint16_t* __restrict__ B2, const float* __restrict__ bias,
    const int* __restrict__ batch, float* __restrict__ gbuf, int row0)
{
  __shared__ char ldsb[131072];
  const int wg = xcd_swz(blockIdx.x, gridDim.x);
  const int mt = wg >> 2, jtg = wg & 3;     // mt: chunk-local 256-row tile; jtg: 256 cols
  const int tid = threadIdx.x;
  const int lane = tid & 63, w = tid >> 6;  // 8 waves
  const int wm = w >> 2, wn = w & 3;        // 2 x 4 wave grid; wave output 128 x 64

  const int aw_row = w * 8 + (lane >> 3);
  const size_t slotb = (size_t)(((lane & 7) ^ (lane >> 3)) << 4);

  auto stageA = [&](int half, int t2){      // A half-tile: rows half*128.. of tile t2
    const char* gb = (t2 < 16) ? (const char*)A0 : (const char*)A1;
    const size_t ktc = (size_t)(t2 & 15) * 128;
    char* lb = ldsb + (t2 & 1) * 65536 + half * 16384 + w * 1024;
    const size_t r0 = (size_t)(mt * 256 + half * 128 + aw_row);
    gll16(gb + r0 * 2048 + ktc + slotb, lb);
    gll16(gb + (r0 + 64) * 2048 + ktc + slotb, lb + 8192);
  };
  auto stageB = [&](int half, int t2){
    const size_t ktc = (size_t)t2 * 128;
    char* lb = ldsb + (t2 & 1) * 65536 + 32768 + half * 16384 + w * 1024;
    const size_t r0 = (size_t)(jtg * 256 + half * 128 + aw_row);
    gll16((const char*)B2 + r0 * 4096 + ktc + slotb, lb);
    gll16((const char*)B2 + (r0 + 64) * 4096 + ktc + slotb, lb + 8192);
  };

  // prologue: tile0 fully + tile1 minus Ah1 (staged at iter0.p0) = 14 loads
  stageB(0, 0); stageB(1, 0); stageA(0, 0); stageA(1, 0);
  stageB(0, 1); stageB(1, 1); stageA(0, 1);
  asm volatile("s_waitcnt vmcnt(6)" ::: "memory");   // tile0 landed; tile1's 6 in flight
  BARRIER();

  f32x4_t acc[8][4] = {};
  const int ks = lane >> 4;
  const int rA = wm * 128 + (lane & 15);
  const int rB = wn * 64 + (lane & 15);

  for (int kt = 0; kt < 32; ++kt){
    const char* lA = ldsb + (kt & 1) * 65536;
    const char* lB = lA + 32768;
    bf16x8_t bg[4][2], af03a[4], af03b[4], af47a[4], af47b[4];
    // ---- phase 0
#pragma unroll
    for (int n = 0; n < 4; n++){
      int r = rB + n * 16;
      bg[n][0] = *(const bf16x8_t*)(lB + r * 128 + ((ks ^ (r & 7)) << 4));
      bg[n][1] = *(const bf16x8_t*)(lB + r * 128 + (((4 + ks) ^ (r & 7)) << 4));
    }
#pragma unroll
    for (int m = 0; m < 4; m++){
      int r = rA + m * 16;
      af03a[m] = *(const bf16x8_t*)(lA + r * 128 + ((ks ^ (r & 7)) << 4));
    }
    if (kt < 31) stageA(1, kt + 1);
    BARRIER();
    __builtin_amdgcn_s_setprio(1);
#pragma unroll
    for (int m = 0; m < 4; m++)
#pragma unroll
      for (int n = 0; n < 4; n++)
        acc[m][n] = __builtin_amdgcn_mfma_f32_16x16x32_bf16(af03a[m], bg[n][0], acc[m][n], 0, 0, 0);
    __builtin_amdgcn_s_setprio(0);
    BARRIER();
    // ---- phase 1
#pragma unroll
    for (int m = 0; m < 4; m++){
      int r = rA + m * 16;
      af03b[m] = *(const bf16x8_t*)(lA + r * 128 + (((4 + ks) ^ (r & 7)) << 4));
    }
#pragma unroll
    for (int m = 0; m < 4; m++){
      int r = rA + 64 + m * 16;
      af47a[m] = *(const bf16x8_t*)(lA + r * 128 + ((ks ^ (r & 7)) << 4));
    }
    if (kt < 30) stageB(0, kt + 2);
    BARRIER();
    __builtin_amdgcn_s_setprio(1);
#pragma unroll
    for (int m = 0; m < 4; m++)
#pragma unroll
      for (int n = 0; n < 4; n++)
        acc[4 + m][n] = __builtin_amdgcn_mfma_f32_16x16x32_bf16(af47a[m], bg[n][0], acc[4 + m][n], 0, 0, 0);
    __builtin_amdgcn_s_setprio(0);
    BARRIER();
    // ---- phase 2
#pragma unroll
    for (int m = 0; m < 4; m++){
      int r = rA + 64 + m * 16;
      af47b[m] = *(const bf16x8_t*)(lA + r * 128 + (((4 + ks) ^ (r & 7)) << 4));
    }
    if (kt < 30) stageB(1, kt + 2);
    BARRIER();
    __builtin_amdgcn_s_setprio(1);
#pragma unroll
    for (int m = 0; m < 4; m++)
#pragma unroll
      for (int n = 0; n < 4; n++)
        acc[m][n] = __builtin_amdgcn_mfma_f32_16x16x32_bf16(af03b[m], bg[n][1], acc[m][n], 0, 0, 0);
    __builtin_amdgcn_s_setprio(0);
    BARRIER();
    // ---- phase 3
    if (kt < 30){
      stageA(0, kt + 2);
      asm volatile("s_waitcnt vmcnt(6)" ::: "memory");
    } else {
      asm volatile("s_waitcnt vmcnt(0)" ::: "memory");
    }
    BARRIER();
    __builtin_amdgcn_s_setprio(1);
#pragma unroll
    for (int m = 0; m < 4; m++)
#pragma unroll
      for (int n = 0; n < 4; n++)
        acc[4 + m][n] = __builtin_amdgcn_mfma_f32_16x16x32_bf16(af47b[m], bg[n][1], acc[4 + m][n], 0, 0, 0);
    __builtin_amdgcn_s_setprio(0);
    BARRIER();
  }

  // epilogue: bias + tanh + segmented pooling (batch sorted)
  const int rowbase = row0 + mt * 256 + wm * 128;
  const int colbase = jtg * 256 + wn * 64;
  int bt[8][4];
#pragma unroll
  for (int mi = 0; mi < 8; mi++)
#pragma unroll
    for (int i = 0; i < 4; i++){
      int R = rowbase + mi * 16 + (lane >> 4) * 4 + i;
      bt[mi][i] = (R < N_NODES) ? batch[R] : -1;
    }
  const int c0 = rowbase       < N_NODES ? rowbase       : N_NODES - 1;
  const int c1 = rowbase + 127 < N_NODES ? rowbase + 127 : N_NODES - 1;
  const int gmin = batch[c0], gmax = batch[c1];

#pragma unroll
  for (int ni = 0; ni < 4; ni++){
    const int col = colbase + ni * 16 + (lane & 15);
    const float bs = bias[col];
    float v[8][4];
#pragma unroll
    for (int mi = 0; mi < 8; mi++)
#pragma unroll
      for (int i = 0; i < 4; i++)
        v[mi][i] = tanhf_fast(acc[mi][ni][i] + bs);
    for (int g = gmin; g <= gmax; g++){
      float s_ = 0.f;
#pragma unroll
      for (int mi = 0; mi < 8; mi++)
#pragma unroll
        for (int i = 0; i < 4; i++)
          s_ += (bt[mi][i] == g) ? v[mi][i] : 0.f;
      s_ += __shfl_xor(s_, 16);
      s_ += __shfl_xor(s_, 32);
      if (lane < 16) atomicAdd(&gbuf[g * DH + col], s_);
    }
  }
}

// ---------------- MLP head ----------------
__global__ void k_head(const float* __restrict__ gbuf, const float* __restrict__ Wf1,
                       const float* __restrict__ bf1, const float* __restrict__ Wf2,
                       const float* __restrict__ bf2, float* __restrict__ out){
  const int gg = blockIdx.x, j = threadIdx.x;
  const float* grow = gbuf + (size_t)gg * DH;
  const float* wr = Wf1 + (size_t)j * DH;
  float acc = bf1[j];
  for (int k = 0; k < DH; k++) acc = fmaf(grow[k], wr[k], acc);
  float y = acc > 0.f ? acc : 0.2f * acc;
  __shared__ float sb[DFC];
  sb[j] = y * Wf2[j];
  __syncthreads();
  for (int off = 64; off > 0; off >>= 1){
    if (j < off) sb[j] += sb[j + off];
    __syncthreads();
  }
  if (j == 0) out[gg] = sb[0] + bf2[0];
}

extern "C" void kernel_launch(void* const* d_in, const int* in_sizes, int n_in,
                              void* d_out, int out_size, void* d_ws, size_t ws_size,
                              hipStream_t stream){
  const float* x   = (const float*)d_in[0];
  const int*   ei  = (const int*)d_in[1];
  const int*   src = ei;
  const int*   dst = ei + N_EDGES;
  const int*   batch = (const int*)d_in[2];
  const float* W1l = (const float*)d_in[3];
  const float* b1l = (const float*)d_in[4];
  const float* W1r = (const float*)d_in[5];
  const float* W2l = (const float*)d_in[6];
  const float* b2l = (const float*)d_in[7];
  const float* W2r = (const float*)d_in[8];
  const float* Wf1 = (const float*)d_in[9];
  const float* bf1 = (const float*)d_in[10];
  const float* Wf2 = (const float*)d_in[11];
  const float* bf2 = (const float*)d_in[12];
  float* out = (float*)d_out;
  (void)in_sizes; (void)n_in; (void)out_size;

  char* ws = (char*)d_ws;
  size_t off = 0;
  auto alloc = [&](size_t bytes) -> void* {
    void* p = (void*)(ws + off);
    off = (off + bytes + 255) & ~(size_t)255;
    return p;
  };
  uint16_t* h1   = (uint16_t*)alloc((size_t)M_PAD * DH * 2);   // 205 MB
  uint16_t* Ap   = (uint16_t*)alloc((size_t)M_PAD * 64 * 2);   // 12.8 MB
  uint16_t* Bp   = (uint16_t*)alloc((size_t)DH * 64 * 2);      // 128 KB
  uint16_t* B2   = (uint16_t*)alloc((size_t)DH * 2048 * 2);    // 4 MB combined [W2l|W2r]
  int*      deg  = (int*)alloc((size_t)N_NODES * 4);
  int*      curs = (int*)alloc((size_t)N_NODES * 4);
  float*    gbuf = (float*)alloc((size_t)NG * DH * 4);
  int*      rowo = (int*)alloc((size_t)(N_NODES + 1) * 4);
  int*      colx = (int*)alloc((size_t)N_EDGES * 4);
  int*      part = (int*)alloc((size_t)NBLK * 4);
  long long remain = (long long)ws_size - (long long)off;
  int chunk_t = (int)(remain / (128LL * 2048LL));
  if (chunk_t > CHUNK_T) chunk_t = CHUNK_T;
  chunk_t &= ~1;                             // gemm tiles are 256 rows = 2 chunk units
  if (chunk_t < 2){
    k_diag<<<1, 64, 0, stream>>>(out, (float)ws_size);
    return;
  }
  uint16_t* aggc = (uint16_t*)alloc((size_t)chunk_t * 128 * DH * 2);

  const size_t zset = (size_t)((char*)gbuf - (char*)deg) + (size_t)NG * DH * 4;
  hipMemsetAsync(deg, 0, zset, stream);   // deg + curs + gbuf in one shot

  k_deg  <<<(N_EDGES + 255) / 256, 256, 0, stream>>>(dst, deg);
  k_scan1<<<NBLK, 256, 0, stream>>>(deg, rowo, part);
  k_scan2<<<1, 512, 0, stream>>>(part, NBLK);
  k_scan3<<<NBLK, 256, 0, stream>>>(rowo, part);
  k_fill <<<(N_EDGES + 255) / 256, 256, 0, stream>>>(src, dst, rowo, curs, colx);
  k_pack <<<NBLK, 256, 0, stream>>>(x, rowo, colx, Ap);
  k_prep <<<4 + 2048, 256, 0, stream>>>(W1l, W1r, Bp, W2l, W2r, B2);
  k_l1g  <<<MTILES * 8, 256, 0, stream>>>(Ap, Bp, b1l, h1);

  for (int t0 = 0; t0 < MTILES; ){
    int ct = MTILES - t0 < chunk_t ? MTILES - t0 : chunk_t;
    int row0 = t0 * 128;
    k_agg2<<<ct * 64, 256, 0, stream>>>(h1, rowo, colx, aggc, row0);
    k_gemm<<<(ct / 2) * 4, 512, 0, stream>>>(aggc, h1 + (size_t)row0 * DH,
                                             B2, b2l, batch, gbuf, row0);
    t0 += ct;
  }
  k_head <<<NG, DFC, 0, stream>>>(gbuf, Wf1, bf1, Wf2, bf2, out);
}